// Round 8
// baseline (167.167 us; speedup 1.0000x reference)
//
#include <hip/hip_runtime.h>
#include <hip/hip_bf16.h>

#define NN   100000
#define KNB  32
#define DIN  256
#define DOUT 128

typedef __attribute__((ext_vector_type(8))) short short8;    // 8 x bf16
typedef __attribute__((ext_vector_type(4))) float f32x4;     // 4 x f32
typedef __attribute__((ext_vector_type(4))) unsigned u32x4;  // 16 B
typedef __attribute__((ext_vector_type(2))) int i32x2;       // 8 B

// v_cvt_pk_bf16_f32: packs 2 f32 -> 2 bf16 (RTNE) in one VALU op (no builtin).
__device__ __forceinline__ unsigned pk2(float a, float b) {
    unsigned r;
    asm("v_cvt_pk_bf16_f32 %0, %1, %2" : "=v"(r) : "v"(a), "v"(b));
    return r;
}

__device__ __forceinline__ short8 cvt8(f32x4 a, f32x4 b) {
    u32x4 t;
    t[0] = pk2(a[0], a[1]);
    t[1] = pk2(a[2], a[3]);
    t[2] = pk2(b[0], b[1]);
    t[3] = pk2(b[2], b[3]);
    return __builtin_bit_cast(short8, t);
}

// ---------------------------------------------------------------------------
// Kernel 0: W [DIN][DOUT] f32  ->  Wt [DOUT][DIN] bf16 (transposed + converted)
// ---------------------------------------------------------------------------
__global__ void wt_conv(const float* __restrict__ W, unsigned short* __restrict__ Wt) {
    int t = blockIdx.x * 256 + threadIdx.x;   // 0 .. 32767
    int d = t >> 8;                           // dout
    int k = t & 255;                          // din
    float v = W[(size_t)k * DOUT + d];
    Wt[t] = (unsigned short)(pk2(v, v) & 0xffffu);
}

// ---------------------------------------------------------------------------
// Kernel 1: h = relu(feats @ W + b), stored bf16 row-major [n][128].
// R7 post-mortem: LDS staging buys NOTHING here — feats rows have zero
// cross-wave reuse (each row feeds exactly one wave), and the per-K-step
// vmcnt(0)+barrier drain plus 2-blocks/CU LDS cap kept it at ~54 µs.
// R6 counters showed the register version was occupancy- and depth-starved
// (22% occ from 1-wave workgroup cap; launch_bounds(64) minimized regs).
// Fix: register streaming — 4-wave blocks, launch_bounds(256,2) (~256 VGPR
// allowed, 8 waves/CU), and the FULL row pair (32 x dwordx4/lane = 512 B
// in flight/lane, 256 KB/CU) issued before the MFMA chain. Pure BW-bound.
// Operand-swapped MFMA: A = Wt (M = DOUT), B = feats^T (N = nodes).
// ---------------------------------------------------------------------------
__global__ __launch_bounds__(256, 2) void gemm_relu(
        const float* __restrict__ feats, const unsigned short* __restrict__ Wt,
        const float* __restrict__ bias, unsigned short* __restrict__ h) {
    const int lane = threadIdx.x & 63;
    const int w    = threadIdx.x >> 6;
    const int l16  = lane & 15;
    const int lq   = lane >> 4;
    const int nodeBase = blockIdx.x * 128 + w * 32;

    int n0 = nodeBase + l16;
    int n1 = nodeBase + 16 + l16;
    int n0c = n0 < NN ? n0 : NN - 1;          // clamp loads; stores predicated
    int n1c = n1 < NN ? n1 : NN - 1;
    const f32x4* f0 = (const f32x4*)(feats + (size_t)n0c * DIN) + lq * 2;
    const f32x4* f1 = (const f32x4*)(feats + (size_t)n1c * DIN) + lq * 2;

    // Load the entire K range up-front: 32 dwordx4, immediate offsets,
    // static indices only (R3 lesson: runtime-indexed arrays -> scratch).
    f32x4 r0[8][2], r1[8][2];
    #pragma unroll
    for (int ks = 0; ks < 8; ++ks) {
        r0[ks][0] = f0[ks * 8];
        r0[ks][1] = f0[ks * 8 + 1];
        r1[ks][0] = f1[ks * 8];
        r1[ks][1] = f1[ks * 8 + 1];
    }

    f32x4 acc[8][2];
    #pragma unroll
    for (int mf = 0; mf < 8; ++mf) { acc[mf][0] = (f32x4)0.f; acc[mf][1] = (f32x4)0.f; }

    const unsigned short* wp = Wt + l16 * DIN + lq * 8;

    #pragma unroll
    for (int ks = 0; ks < 8; ++ks) {
        short8 bf0 = cvt8(r0[ks][0], r0[ks][1]);
        short8 bf1 = cvt8(r1[ks][0], r1[ks][1]);
        #pragma unroll
        for (int mf = 0; mf < 8; ++mf) {
            short8 a = *(const short8*)(wp + mf * 16 * DIN + ks * 32);
            acc[mf][0] = __builtin_amdgcn_mfma_f32_16x16x32_bf16(a, bf0, acc[mf][0], 0, 0, 0);
            acc[mf][1] = __builtin_amdgcn_mfma_f32_16x16x32_bf16(a, bf1, acc[mf][1], 0, 0, 0);
        }
    }

    // Epilogue: bias + relu + pack 4 bf16 -> 8 B store (row-major h).
    // D layout: col (node) = lane&15, row (dout) = (lane>>4)*4 + reg  [m89]
    #pragma unroll
    for (int mf = 0; mf < 8; ++mf) {
        int dbase = mf * 16 + lq * 4;
        f32x4 bv = *(const f32x4*)(bias + dbase);
        #pragma unroll
        for (int nf = 0; nf < 2; ++nf) {
            int node = nodeBase + nf * 16 + l16;
            if (node < NN) {
                f32x4 v = acc[mf][nf];
                float v0 = fmaxf(v[0] + bv[0], 0.f);
                float v1 = fmaxf(v[1] + bv[1], 0.f);
                float v2 = fmaxf(v[2] + bv[2], 0.f);
                float v3 = fmaxf(v[3] + bv[3], 0.f);
                uint2 st = make_uint2(pk2(v0, v1), pk2(v2, v3));
                *(uint2*)(h + (size_t)node * DOUT + dbase) = st;
            }
        }
    }
}

// ---------------------------------------------------------------------------
// Kernel 2: out[n] = mean_k h_bf16[edge[n][k]]   (R5 version: 107 µs, pinned
// at ~3.8 TB/s L2-fill across three structurally different implementations
// -> fill-path BW ceiling; only traffic reduction could beat it.)
// Quarter-wave per node, 16 B dwordx4 per lane, 8-deep NAMED-reg pipeline.
// ---------------------------------------------------------------------------
__global__ __launch_bounds__(256) void gather_mean(
        const int* __restrict__ edge, const unsigned short* __restrict__ h,
        float* __restrict__ out) {
    const int q = threadIdx.x & 15;
    const int n = blockIdx.x * 16 + (threadIdx.x >> 4);   // 6250*16 == NN exactly

    i32x2 e2 = __builtin_nontemporal_load((const i32x2*)(edge + n * KNB + q * 2));

    float s0=0,s1=0,s2=0,s3=0,s4=0,s5=0,s6=0,s7=0;

    #define ROW(k) ((size_t)((k) < 16 ? __shfl(e2[0], (k), 16) \
                                      : __shfl(e2[1], (k) - 16, 16)) * DOUT)
    #define LD(k)  (*(const u32x4*)(h + ROW(k) + q * 8))
    #define ACC(v) do { \
        s0 += __uint_as_float((v)[0] << 16); \
        s1 += __uint_as_float((v)[0] & 0xffff0000u); \
        s2 += __uint_as_float((v)[1] << 16); \
        s3 += __uint_as_float((v)[1] & 0xffff0000u); \
        s4 += __uint_as_float((v)[2] << 16); \
        s5 += __uint_as_float((v)[2] & 0xffff0000u); \
        s6 += __uint_as_float((v)[3] << 16); \
        s7 += __uint_as_float((v)[3] & 0xffff0000u); } while (0)
    #define STEP(k, B) do { u32x4 v_ = (B); \
        if ((k) + 8 < KNB) (B) = LD((k) + 8); \
        ACC(v_); } while (0)

    u32x4 b0 = LD(0), b1 = LD(1), b2 = LD(2), b3 = LD(3);
    u32x4 b4 = LD(4), b5 = LD(5), b6 = LD(6), b7 = LD(7);

    STEP( 0, b0); STEP( 1, b1); STEP( 2, b2); STEP( 3, b3);
    STEP( 4, b4); STEP( 5, b5); STEP( 6, b6); STEP( 7, b7);
    STEP( 8, b0); STEP( 9, b1); STEP(10, b2); STEP(11, b3);
    STEP(12, b4); STEP(13, b5); STEP(14, b6); STEP(15, b7);
    STEP(16, b0); STEP(17, b1); STEP(18, b2); STEP(19, b3);
    STEP(20, b4); STEP(21, b5); STEP(22, b6); STEP(23, b7);
    STEP(24, b0); STEP(25, b1); STEP(26, b2); STEP(27, b3);
    STEP(28, b4); STEP(29, b5); STEP(30, b6); STEP(31, b7);

    #undef STEP
    #undef ACC
    #undef LD
    #undef ROW

    const float sc = 1.f / KNB;
    f32x4 o0 = { s0 * sc, s1 * sc, s2 * sc, s3 * sc };
    f32x4 o1 = { s4 * sc, s5 * sc, s6 * sc, s7 * sc };
    float* op = out + (size_t)n * DOUT + q * 8;
    __builtin_nontemporal_store(o0, (f32x4*)op);
    __builtin_nontemporal_store(o1, (f32x4*)(op + 4));
}

// ---------------------------------------------------------------------------
extern "C" void kernel_launch(void* const* d_in, const int* in_sizes, int n_in,
                              void* d_out, int out_size, void* d_ws, size_t ws_size,
                              hipStream_t stream) {
    const float* feats = (const float*)d_in[0];   // [100000,256] f32
    const int*   edge  = (const int*)d_in[1];     // [100000,32] i32
    const float* W     = (const float*)d_in[2];   // [256,128] f32
    const float* b     = (const float*)d_in[3];   // [128] f32
    float* out = (float*)d_out;                   // [100000,128] f32

    unsigned short* Wt = (unsigned short*)d_ws;                    // 64 KB
    unsigned short* h  = (unsigned short*)((char*)d_ws + 65536);   // 25.6 MB row-major

    wt_conv<<<128, 256, 0, stream>>>(W, Wt);
    gemm_relu<<<(NN + 127) / 128, 256, 0, stream>>>(feats, Wt, b, h);
    gather_mean<<<NN / 16, 256, 0, stream>>>(edge, h, out);
}

// Round 9
// 151.778 us; speedup vs baseline: 1.1014x; 1.1014x over previous
//
#include <hip/hip_runtime.h>
#include <hip/hip_bf16.h>

#define NN   100000
#define KNB  32
#define DIN  256
#define DOUT 128

typedef __attribute__((ext_vector_type(8))) short short8;    // 8 x bf16
typedef __attribute__((ext_vector_type(4))) float f32x4;     // 4 x f32
typedef __attribute__((ext_vector_type(4))) unsigned u32x4;  // 16 B
typedef __attribute__((ext_vector_type(2))) int i32x2;       // 8 B

// v_cvt_pk_bf16_f32: packs 2 f32 -> 2 bf16 (RTNE) in one VALU op (no builtin).
__device__ __forceinline__ unsigned pk2(float a, float b) {
    unsigned r;
    asm("v_cvt_pk_bf16_f32 %0, %1, %2" : "=v"(r) : "v"(a), "v"(b));
    return r;
}

__device__ __forceinline__ short8 cvt8(f32x4 a, f32x4 b) {
    u32x4 t;
    t[0] = pk2(a[0], a[1]);
    t[1] = pk2(a[2], a[3]);
    t[2] = pk2(b[0], b[1]);
    t[3] = pk2(b[2], b[3]);
    return __builtin_bit_cast(short8, t);
}

// async global->LDS, 16 B per lane. LDS dest is wave-uniform base + lane*16.
__device__ __forceinline__ void load_lds16(const float* g, float* l) {
    __builtin_amdgcn_global_load_lds(
        (const __attribute__((address_space(1))) void*)g,
        (__attribute__((address_space(3))) void*)l, 16, 0, 0);
}

// ---------------------------------------------------------------------------
// Kernel 0: W [DIN][DOUT] f32  ->  Wt [DOUT][DIN] bf16 (transposed + converted)
// ---------------------------------------------------------------------------
__global__ void wt_conv(const float* __restrict__ W, unsigned short* __restrict__ Wt) {
    int t = blockIdx.x * 256 + threadIdx.x;   // 0 .. 32767
    int d = t >> 8;                           // dout
    int k = t & 255;                          // din
    float v = W[(size_t)k * DOUT + d];
    Wt[t] = (unsigned short)(pk2(v, v) & 0xffffu);
}

// ---------------------------------------------------------------------------
// Kernel 1: h = relu(feats @ W + b), bf16 row-major [n][128].
// R8 post-mortem: every prior version re-read the full 64 KB Wt from global
// per wave (L1 = 32 KB -> guaranteed thrash), serialized into the MFMA chain.
// New decomposition: block = 32 nodes x 4 waves; wave w owns douts
// [32w,32w+32) -> its Wt slice is 16 KB = 64 VGPR loaded UP-FRONT (16 dwordx4,
// L2-hot). feats staged once per block into 32 KB LDS with genuine 4x reuse
// (all waves read all 32 rows); ONE vmcnt(0)+barrier per block, no K-drains.
// Swizzle both sides (rule #21): chunk ^= (row&7) on global source + ds_read.
// ~115 VGPR (launch_bounds(256,4) caps 128) + 32 KB LDS -> 4 blocks/CU, so
// staging latency hides under other blocks' compute (m114).
// Operand-swapped MFMA: A = Wt (M = douts), B = feats^T (N = nodes).
// ---------------------------------------------------------------------------
__global__ __launch_bounds__(256, 4) void gemm_relu(
        const float* __restrict__ feats, const unsigned short* __restrict__ Wt,
        const float* __restrict__ bias, unsigned short* __restrict__ h) {
    __shared__ float sf[32 * DIN];            // 32 KB: 32 node rows x 256 f32

    const int tid  = threadIdx.x;
    const int lane = tid & 63;
    const int w    = tid >> 6;                // wave = dout group
    const int l16  = lane & 15;
    const int lq   = lane >> 4;
    const int blockBase = blockIdx.x * 32;    // 3125 * 32 == 100000 exactly

    // (1) Wt slice for this wave's 32 douts: afrag[m][ks], 64 VGPR, issued first.
    short8 afrag[2][8];
    const unsigned short* wp = Wt + (size_t)(w * 32 + l16) * DIN + lq * 8;
    #pragma unroll
    for (int m = 0; m < 2; ++m)
        #pragma unroll
        for (int ks = 0; ks < 8; ++ks)
            afrag[m][ks] = *(const short8*)(wp + m * 16 * DIN + ks * 32);

    // (2) Stage 32 feats rows (32 KB) via global_load_lds, swizzled source.
    // Instr it: thread tid -> dest byte it*4096 + tid*16 (lane-linear), i.e.
    // row = it*4 + w, dest chunk cd = lane (0..63 of 16 B chunks per row).
    #pragma unroll
    for (int it = 0; it < 8; ++it) {
        int row = it * 4 + w;
        int cd  = lane;
        int cs  = cd ^ (row & 7);             // inverse-swizzled global source
        load_lds16(feats + (size_t)(blockBase + row) * DIN + cs * 4,
                   sf + it * 1024 + tid * 4);
    }

    asm volatile("s_waitcnt vmcnt(0)" ::: "memory");   // LDS queue drained
    __syncthreads();

    // (3) MFMA: 8 ks x (2 node-groups cvt + 2 mf) = 32 MFMA/wave.
    f32x4 acc[2][2];
    acc[0][0] = (f32x4)0.f; acc[0][1] = (f32x4)0.f;
    acc[1][0] = (f32x4)0.f; acc[1][1] = (f32x4)0.f;

    #pragma unroll
    for (int ks = 0; ks < 8; ++ks) {
        short8 bf0, bf1;
        {
            const float* rbase = sf + (size_t)l16 * DIN;
            f32x4 x0 = *(const f32x4*)(rbase + ((ks * 8 + 2 * lq)     ^ (l16 & 7)) * 4);
            f32x4 x1 = *(const f32x4*)(rbase + ((ks * 8 + 2 * lq + 1) ^ (l16 & 7)) * 4);
            bf0 = cvt8(x0, x1);
        }
        {
            const float* rbase = sf + (size_t)(16 + l16) * DIN;
            f32x4 x0 = *(const f32x4*)(rbase + ((ks * 8 + 2 * lq)     ^ (l16 & 7)) * 4);
            f32x4 x1 = *(const f32x4*)(rbase + ((ks * 8 + 2 * lq + 1) ^ (l16 & 7)) * 4);
            bf1 = cvt8(x0, x1);
        }
        #pragma unroll
        for (int m = 0; m < 2; ++m) {
            acc[m][0] = __builtin_amdgcn_mfma_f32_16x16x32_bf16(afrag[m][ks], bf0, acc[m][0], 0, 0, 0);
            acc[m][1] = __builtin_amdgcn_mfma_f32_16x16x32_bf16(afrag[m][ks], bf1, acc[m][1], 0, 0, 0);
        }
    }

    // (4) Epilogue: bias + relu + pack; wave writes its own 32-dout stripe.
    // D layout: col (node) = lane&15, row (dout) = (lane>>4)*4 + reg  [m89]
    #pragma unroll
    for (int m = 0; m < 2; ++m) {
        int dbase = w * 32 + m * 16 + lq * 4;
        f32x4 bv = *(const f32x4*)(bias + dbase);
        #pragma unroll
        for (int nf = 0; nf < 2; ++nf) {
            int node = blockBase + nf * 16 + l16;
            f32x4 v = acc[m][nf];
            float v0 = fmaxf(v[0] + bv[0], 0.f);
            float v1 = fmaxf(v[1] + bv[1], 0.f);
            float v2 = fmaxf(v[2] + bv[2], 0.f);
            float v3 = fmaxf(v[3] + bv[3], 0.f);
            uint2 st = make_uint2(pk2(v0, v1), pk2(v2, v3));
            *(uint2*)(h + (size_t)node * DOUT + dbase) = st;
        }
    }
}

// ---------------------------------------------------------------------------
// Kernel 2: out[n] = mean_k h_bf16[edge[n][k]]   (R5 form, fill-BW-bound at
// ~3.8 TB/s). Split into 2 half-node dispatches purely so gemm_relu becomes
// visible in the rocprof top-5 (each half ~54 µs).
// ---------------------------------------------------------------------------
__global__ __launch_bounds__(256) void gather_mean(
        const int* __restrict__ edge, const unsigned short* __restrict__ h,
        float* __restrict__ out, int nbase) {
    const int q = threadIdx.x & 15;
    const int n = nbase + blockIdx.x * 16 + (threadIdx.x >> 4);

    i32x2 e2 = __builtin_nontemporal_load((const i32x2*)(edge + (size_t)n * KNB + q * 2));

    float s0=0,s1=0,s2=0,s3=0,s4=0,s5=0,s6=0,s7=0;

    #define ROW(k) ((size_t)((k) < 16 ? __shfl(e2[0], (k), 16) \
                                      : __shfl(e2[1], (k) - 16, 16)) * DOUT)
    #define LD(k)  (*(const u32x4*)(h + ROW(k) + q * 8))
    #define ACC(v) do { \
        s0 += __uint_as_float((v)[0] << 16); \
        s1 += __uint_as_float((v)[0] & 0xffff0000u); \
        s2 += __uint_as_float((v)[1] << 16); \
        s3 += __uint_as_float((v)[1] & 0xffff0000u); \
        s4 += __uint_as_float((v)[2] << 16); \
        s5 += __uint_as_float((v)[2] & 0xffff0000u); \
        s6 += __uint_as_float((v)[3] << 16); \
        s7 += __uint_as_float((v)[3] & 0xffff0000u); } while (0)
    #define STEP(k, B) do { u32x4 v_ = (B); \
        if ((k) + 8 < KNB) (B) = LD((k) + 8); \
        ACC(v_); } while (0)

    u32x4 b0 = LD(0), b1 = LD(1), b2 = LD(2), b3 = LD(3);
    u32x4 b4 = LD(4), b5 = LD(5), b6 = LD(6), b7 = LD(7);

    STEP( 0, b0); STEP( 1, b1); STEP( 2, b2); STEP( 3, b3);
    STEP( 4, b4); STEP( 5, b5); STEP( 6, b6); STEP( 7, b7);
    STEP( 8, b0); STEP( 9, b1); STEP(10, b2); STEP(11, b3);
    STEP(12, b4); STEP(13, b5); STEP(14, b6); STEP(15, b7);
    STEP(16, b0); STEP(17, b1); STEP(18, b2); STEP(19, b3);
    STEP(20, b4); STEP(21, b5); STEP(22, b6); STEP(23, b7);
    STEP(24, b0); STEP(25, b1); STEP(26, b2); STEP(27, b3);
    STEP(28, b4); STEP(29, b5); STEP(30, b6); STEP(31, b7);

    #undef STEP
    #undef ACC
    #undef LD
    #undef ROW

    const float sc = 1.f / KNB;
    f32x4 o0 = { s0 * sc, s1 * sc, s2 * sc, s3 * sc };
    f32x4 o1 = { s4 * sc, s5 * sc, s6 * sc, s7 * sc };
    float* op = out + (size_t)n * DOUT + q * 8;
    __builtin_nontemporal_store(o0, (f32x4*)op);
    __builtin_nontemporal_store(o1, (f32x4*)(op + 4));
}

// ---------------------------------------------------------------------------
extern "C" void kernel_launch(void* const* d_in, const int* in_sizes, int n_in,
                              void* d_out, int out_size, void* d_ws, size_t ws_size,
                              hipStream_t stream) {
    const float* feats = (const float*)d_in[0];   // [100000,256] f32
    const int*   edge  = (const int*)d_in[1];     // [100000,32] i32
    const float* W     = (const float*)d_in[2];   // [256,128] f32
    const float* b     = (const float*)d_in[3];   // [128] f32
    float* out = (float*)d_out;                   // [100000,128] f32

    unsigned short* Wt = (unsigned short*)d_ws;                    // 64 KB
    unsigned short* h  = (unsigned short*)((char*)d_ws + 65536);   // 25.6 MB row-major

    wt_conv<<<128, 256, 0, stream>>>(W, Wt);
    gemm_relu<<<NN / 32, 256, 0, stream>>>(feats, Wt, b, h);
    gather_mean<<<(NN / 2) / 16, 256, 0, stream>>>(edge, h, out, 0);
    gather_mean<<<(NN / 2) / 16, 256, 0, stream>>>(edge, h, out, NN / 2);
}